// Round 17
// baseline (877.304 us; speedup 1.0000x reference)
//
#include <hip/hip_runtime.h>
#include <hip/hip_bf16.h>

#define N_ATOMS 400000
#define MAX_D   4
#define NDEG_   5
#define B_GR    16384
#define NTASK   12
#define AT      256                 // bin alignment
#define TA      64                  // atoms per conv tile (divides AT)
#define NTHR    512                 // 8 waves (conv2-4)
#define PADCAP  401408              // 1568 * 256 >= N + 5*(AT-1)

// 4-byte-aligned float4 for row chunks (rows are 4B-aligned only).
typedef float float4u __attribute__((ext_vector_type(4), aligned(4)));

__device__ __forceinline__ float selu_f(float x) {
    const float a = 1.6732632423543772f, s = 1.0507009873554805f;
    return x > 0.f ? s * x : s * a * (__expf(x) - 1.f);
}

__device__ __forceinline__ unsigned short f2bf(float x) {   // RNE
    unsigned int u = __float_as_uint(x);
    return (unsigned short)((u + 0x7FFFu + ((u >> 16) & 1u)) >> 16);
}
__device__ __forceinline__ float bf2f(unsigned int s) {
    return __uint_as_float(s << 16);
}

// ===================== degree-sort prep =====================
// ctr layout (ints): [0..4] counts, [5..9] cursor, [10..15] bin offsets
__global__ void zero_kernel(int* ctr) {
    if (threadIdx.x < 10) ctr[threadIdx.x] = 0;
}

__launch_bounds__(256)
__global__ void fill_kernel(int* idx, int* degs_s, int4* nbrs_s, int4* nbro_s) {
    const int e = blockIdx.x * 256 + threadIdx.x;
    if (e < PADCAP) {
        idx[e] = -1;
        degs_s[e] = -1;
        nbrs_s[e] = make_int4(0, 0, 0, 0);
        nbro_s[e] = make_int4(0, 0, 0, 0);
    }
}

__launch_bounds__(256)
__global__ void hist_kernel(const int* __restrict__ deg, int* ctr) {
    __shared__ int h[NDEG_];
    if (threadIdx.x < NDEG_) h[threadIdx.x] = 0;
    __syncthreads();
    for (int i = blockIdx.x * 256 + threadIdx.x; i < N_ATOMS; i += gridDim.x * 256)
        atomicAdd(&h[deg[i]], 1);
    __syncthreads();
    if (threadIdx.x < NDEG_ && h[threadIdx.x]) atomicAdd(&ctr[threadIdx.x], h[threadIdx.x]);
}

__global__ void offsets_kernel(int* ctr) {
    if (threadIdx.x == 0) {
        int run = 0;
        for (int d = 0; d < NDEG_; ++d) {
            ctr[10 + d] = run;
            run += ctr[d];
            run = (run + AT - 1) & ~(AT - 1);
        }
        ctr[15] = run;
    }
}

__launch_bounds__(256)
__global__ void scatter_kernel(const int* __restrict__ deg, int* ctr,
                               int* idx, int* rank, int* degs_s) {
    __shared__ int h[NDEG_];
    __shared__ int base[NDEG_];
    const int i = blockIdx.x * 256 + threadIdx.x;
    const int d = (i < N_ATOMS) ? deg[i] : -1;
    if (threadIdx.x < NDEG_) h[threadIdx.x] = 0;
    __syncthreads();
    int intra = 0;
    if (i < N_ATOMS) intra = atomicAdd(&h[d], 1);            // LDS atomic
    __syncthreads();
    if (threadIdx.x < NDEG_ && h[threadIdx.x] > 0)
        base[threadIdx.x] = atomicAdd(&ctr[5 + threadIdx.x], h[threadIdx.x]);
    __syncthreads();
    if (i < N_ATOMS) {
        const int p = ctr[10 + d] + base[d] + intra;
        idx[p] = i;
        rank[i] = p;
        degs_s[p] = d;
    }
}

__launch_bounds__(256)
__global__ void nbrprep_kernel(const int* __restrict__ nbr, const int* __restrict__ rank,
                               int4* __restrict__ nbrs_s, int4* __restrict__ nbro_s) {
    const int i = blockIdx.x * 256 + threadIdx.x;
    if (i >= N_ATOMS) return;
    const int p = rank[i];
    const int4 nb = *reinterpret_cast<const int4*>(nbr + (size_t)i * MAX_D);
    nbro_s[p] = nb;
    nbrs_s[p] = make_int4(rank[nb.x], rank[nb.y], rank[nb.z], rank[nb.w]);
}

// ===================== conv1 split: project -> gather-combine =====================
// R16 post-mortem fixes:
//  (1) wave imbalance (Z waves 15 cols vs S waves 4) -> each of 4 waves now
//      computes ONE fused 19-col pass: Z plane w (15 cols, Wn1[w+1]) + S
//      chunk w*4 (4 cols, Ws1[d_tile]). Balanced, 256-thread blocks,
//      8 blocks/CU at 19.5KB LDS = 100% occupancy.
//  (2) VGPR=12 serialization -> f-loop grouped 3 float4-chunks per step and
//      fully unrolled: multiple b128 LDS reads in flight feeding 19 FMAs each.
__launch_bounds__(256)
__global__ void conv1_project(const float* __restrict__ af,
                              const float* __restrict__ Ws1,
                              const float* __restrict__ Wn1,
                              const float* __restrict__ b1,
                              const int*   __restrict__ degs_s,
                              const int*   __restrict__ idx,
                              float*       __restrict__ S,        // [PADCAP][16] fp32
                              unsigned short* __restrict__ Z)     // [4][PADCAP][16] bf16
{
    __shared__ float xt[TA][76];
    __shared__ int s_a[TA];

    const int pb = blockIdx.x * TA;
    const int dfirst = degs_s[pb];
    if (dfirst < 0) return;                       // whole tile is padding
    const int tid = threadIdx.x;

    if (tid < TA) {
        int a = idx[pb + tid];
        s_a[tid] = (a < 0) ? 0 : a;               // padding: dummy row 0
    }
    __syncthreads();

    // phase A: stage own rows, float4 coalesced (FULL=18, REM=3)
    #pragma unroll 2
    for (int e = tid; e < TA * 18; e += 256) {
        const int al = e / 18, f4 = e - al * 18;
        *(float4u*)&xt[al][f4 * 4] = *(const float4u*)(af + (size_t)s_a[al] * 75 + f4 * 4);
    }
    for (int e = tid; e < TA * 3; e += 256) {
        const int al = e / 3, r = e - al * 3;
        xt[al][72 + r] = af[(size_t)s_a[al] * 75 + 72 + r];
    }
    __syncthreads();

    // phase B: wave w -> Z plane w (d=w+1) AND S chunk w*4, fused 19-col pass
    const int w = __builtin_amdgcn_readfirstlane(tid >> 6);   // SGPR
    const int l = tid & 63;
    const int d = __builtin_amdgcn_readfirstlane(dfirst);
    const int o0 = w * 4;                                     // SGPR
    const float* __restrict__ wn  = Wn1 + (size_t)(w + 1) * 75 * 15;  // Z weights
    const float* __restrict__ wsp = Ws1 + (size_t)d * 75 * 15 + o0;   // S weights
    const float* __restrict__ bb  = b1 + d * 15 + o0;

    float accz[15];
    #pragma unroll
    for (int o = 0; o < 15; ++o) accz[o] = 0.f;
    float accs[4];
    #pragma unroll
    for (int oo = 0; oo < 4; ++oo) accs[oo] = (o0 + oo < 15) ? bb[oo] : 0.f;

    // 18 float4 chunks in 6 groups of 3 (ILP: 3 b128 reads in flight) + 3 tail
    #pragma unroll
    for (int g = 0; g < 6; ++g) {
        const float4u c0 = *(const float4u*)&xt[l][(g * 3 + 0) * 4];
        const float4u c1 = *(const float4u*)&xt[l][(g * 3 + 1) * 4];
        const float4u c2 = *(const float4u*)&xt[l][(g * 3 + 2) * 4];
        #pragma unroll
        for (int c = 0; c < 3; ++c) {
            const float4u xv = (c == 0) ? c0 : (c == 1) ? c1 : c2;
            #pragma unroll
            for (int k = 0; k < 4; ++k) {
                const int f = (g * 3 + c) * 4 + k;
                const float* __restrict__ wfz = wn + f * 15;
                const float* __restrict__ wfs = wsp + f * 15;
                #pragma unroll
                for (int o = 0; o < 15; ++o) accz[o] = fmaf(xv[k], wfz[o], accz[o]);
                #pragma unroll
                for (int oo = 0; oo < 4; ++oo)
                    if (o0 + oo < 15) accs[oo] = fmaf(xv[k], wfs[oo], accs[oo]);
            }
        }
    }
    #pragma unroll
    for (int k = 0; k < 3; ++k) {
        const float xv = xt[l][72 + k];
        const float* __restrict__ wfz = wn + (72 + k) * 15;
        const float* __restrict__ wfs = wsp + (72 + k) * 15;
        #pragma unroll
        for (int o = 0; o < 15; ++o) accz[o] = fmaf(xv, wfz[o], accz[o]);
        #pragma unroll
        for (int oo = 0; oo < 4; ++oo)
            if (o0 + oo < 15) accs[oo] = fmaf(xv, wfs[oo], accs[oo]);
    }

    // store Z row (bf16, 32B) for plane w
    unsigned short zr[16];
    #pragma unroll
    for (int o = 0; o < 15; ++o) zr[o] = f2bf(accz[o]);
    zr[15] = 0;
    unsigned short* zp = Z + ((size_t)w * PADCAP + pb + l) * 16;
    ((int4*)zp)[0] = ((const int4*)zr)[0];
    ((int4*)zp)[1] = ((const int4*)zr)[1];

    // store S chunk (fp32, 16B)
    float4u sv = {accs[0], accs[1], accs[2], accs[3]};
    *(float4u*)(S + (size_t)(pb + l) * 16 + o0) = sv;
}

// K2 v2: thread = (atom, quad). 4x concurrency vs R16's one-thread-per-atom.
// S: lanes of one atom read consecutive 16B -> perfectly coalesced.
// Z: each lane reads 8B of the neighbor's 32B row; 4 lanes reassemble it.
template<int DEG>
__device__ __forceinline__ void combine_body(const float* __restrict__ S,
                                             const unsigned short* __restrict__ Z,
                                             const int4* __restrict__ nbrs_s,
                                             float* __restrict__ x1, int p, int q)
{
    const int o0 = q * 4;
    float4u acc = *(const float4u*)(S + (size_t)p * 16 + o0);

    if (DEG > 0) {
        const int4 nb = nbrs_s[p];
        const int nbid[4] = {nb.x, nb.y, nb.z, nb.w};
        #pragma unroll
        for (int j = 0; j < DEG; ++j) {
            const unsigned short* zp =
                Z + ((size_t)(DEG - 1) * PADCAP + nbid[j]) * 16 + o0;
            const uint2 zz = *(const uint2*)zp;                // 4 bf16 = 8B
            acc[0] += bf2f(zz.x & 0xffffu);
            acc[1] += bf2f(zz.x >> 16);
            acc[2] += bf2f(zz.y & 0xffffu);
            acc[3] += bf2f(zz.y >> 16);
        }
    }
    #pragma unroll
    for (int k = 0; k < 4; ++k)
        if (o0 + k < 15) x1[(size_t)p * 15 + o0 + k] = selu_f(acc[k]);
}

__launch_bounds__(256)
__global__ void conv1_combine(const float* __restrict__ S,
                              const unsigned short* __restrict__ Z,
                              const int4* __restrict__ nbrs_s,
                              const int*  __restrict__ degs_s,
                              float*      __restrict__ x1)
{
    const int base = blockIdx.x * 64;             // 64 atoms x 4 quads = 256 threads
    const int dfirst = degs_s[base];
    if (dfirst < 0) return;
    const int p = base + (threadIdx.x >> 2);
    const int q = threadIdx.x & 3;
    switch (__builtin_amdgcn_readfirstlane(dfirst)) {
    case 0: combine_body<0>(S, Z, nbrs_s, x1, p, q); break;
    case 1: combine_body<1>(S, Z, nbrs_s, x1, p, q); break;
    case 2: combine_body<2>(S, Z, nbrs_s, x1, p, q); break;
    case 3: combine_body<3>(S, Z, nbrs_s, x1, p, q); break;
    default: combine_body<4>(S, Z, nbrs_s, x1, p, q); break;
    }
}

// ===================== conv layers 2-4 (R14-proven scalar, odd FIP) =====================
template<int FI, int FIP, int FO, bool SCATTER_OUT, int DEG>
__device__ __forceinline__ void conv_body(const float* __restrict__ x,
                                          const float* __restrict__ Ws,
                                          const float* __restrict__ Wn,
                                          const float* __restrict__ bias,
                                          const int*   __restrict__ idx,
                                          float*       __restrict__ outs,
                                          float (*__restrict__ xt)[FIP],
                                          float (*__restrict__ nt)[FIP],
                                          const int*  s_a,
                                          const int4* s_nb,
                                          int pb, int tid)
{
    #pragma unroll 2
    for (int e = tid; e < TA * FI; e += NTHR) {
        const int al = e / FI, f = e - al * FI;
        const int4 nb = s_nb[al];
        const float xv = x[(size_t)s_a[al] * FI + f];
        float s = 0.f;
        if (DEG > 0) s += x[(size_t)nb.x * FI + f];
        if (DEG > 1) s += x[(size_t)nb.y * FI + f];
        if (DEG > 2) s += x[(size_t)nb.z * FI + f];
        if (DEG > 3) s += x[(size_t)nb.w * FI + f];
        xt[al][f] = xv;
        nt[al][f] = s;
    }
    __syncthreads();

    const int w = __builtin_amdgcn_readfirstlane(tid >> 6);   // wave id, SGPR
    const int l = tid & 63;                                   // lane = atom
    constexpr int OPG = (FO + 7) / 8;
    const int o0 = w * OPG;                                   // SGPR
    const float* __restrict__ wsd = Ws + (DEG * FI) * FO + o0;
    const float* __restrict__ wnd = Wn + (DEG * FI) * FO + o0;
    const float* __restrict__ bb  = bias + DEG * FO + o0;

    float acc[OPG];
    #pragma unroll
    for (int oo = 0; oo < OPG; ++oo)
        acc[oo] = (o0 + oo < FO) ? bb[oo] : 0.f;

    for (int f = 0; f < FI; ++f) {
        const float xv = xt[l][f];
        const float nv = nt[l][f];
        const float* __restrict__ wsf = wsd + f * FO;
        const float* __restrict__ wnf = wnd + f * FO;
        #pragma unroll
        for (int oo = 0; oo < OPG; ++oo) {
            if (o0 + oo < FO)
                acc[oo] = fmaf(xv, wsf[oo], fmaf(nv, wnf[oo], acc[oo]));
        }
    }

    int row; bool store;
    if (SCATTER_OUT) { row = idx[pb + l]; store = (row >= 0); }
    else             { row = pb + l;      store = true; }
    if (store) {
        float* __restrict__ orow = outs + (size_t)row * FO + o0;
        #pragma unroll
        for (int oo = 0; oo < OPG; ++oo)
            if (o0 + oo < FO) orow[oo] = selu_f(acc[oo]);
    }
}

template<int FI, int FIP, int FO, bool SCATTER_OUT>
__launch_bounds__(NTHR)
__global__ void conv_fused5(const float* __restrict__ x,
                            const int4*  __restrict__ nbr_,
                            const float* __restrict__ Ws,
                            const float* __restrict__ Wn,
                            const float* __restrict__ bias,
                            const int*   __restrict__ degs_s,
                            const int*   __restrict__ idx,
                            float*       __restrict__ outs)
{
    __shared__ float xt[TA][FIP];
    __shared__ float nt[TA][FIP];
    __shared__ int   s_a[TA];
    __shared__ int4  s_nb[TA];

    const int pb = blockIdx.x * TA;
    const int dfirst = degs_s[pb];
    if (dfirst < 0) return;
    const int tid = threadIdx.x;

    if (tid < TA) {
        const int p = pb + tid;
        s_a[tid] = p;
        s_nb[tid] = nbr_[p];
    }
    __syncthreads();

    switch (__builtin_amdgcn_readfirstlane(dfirst)) {
    case 0: conv_body<FI, FIP, FO, SCATTER_OUT, 0>(x, Ws, Wn, bias, idx, outs, xt, nt, s_a, s_nb, pb, tid); break;
    case 1: conv_body<FI, FIP, FO, SCATTER_OUT, 1>(x, Ws, Wn, bias, idx, outs, xt, nt, s_a, s_nb, pb, tid); break;
    case 2: conv_body<FI, FIP, FO, SCATTER_OUT, 2>(x, Ws, Wn, bias, idx, outs, xt, nt, s_a, s_nb, pb, tid); break;
    case 3: conv_body<FI, FIP, FO, SCATTER_OUT, 3>(x, Ws, Wn, bias, idx, outs, xt, nt, s_a, s_nb, pb, tid); break;
    default: conv_body<FI, FIP, FO, SCATTER_OUT, 4>(x, Ws, Wn, bias, idx, outs, xt, nt, s_a, s_nb, pb, tid); break;
    }
}

// ===================== GraphGather readout + softmax head =====================
__launch_bounds__(64)
__global__ void readout_kernel(const float* __restrict__ x4o,
                               const int*   __restrict__ mem,
                               const float* __restrict__ Wd2,
                               const float* __restrict__ bd2,
                               float*       __restrict__ p)
{
    const int g = blockIdx.x;
    const int t = threadIdx.x;

    int lo = 0, hi = N_ATOMS;                    // lower_bound(g)
    while (lo < hi) { int mid = (lo + hi) >> 1; if (mem[mid] < g) lo = mid + 1; else hi = mid; }
    int lo2 = lo, hi2 = N_ATOMS;                 // lower_bound(g+1)
    while (lo2 < hi2) { int mid = (lo2 + hi2) >> 1; if (mem[mid] < g + 1) lo2 = mid + 1; else hi2 = mid; }

    __shared__ float r[72];
    if (t < 36) {
        float s = 0.f, m = -3.4e38f;
        for (int a = lo; a < lo2; ++a) {
            float v = x4o[(size_t)a * 36 + t];
            s += v;
            m = fmaxf(m, v);
        }
        if (lo2 == lo) m = 0.f;                  // empty graph -> 0
        r[t]      = selu_f(s);
        r[36 + t] = selu_f(m);
    }
    __syncthreads();
    if (t < 24) {
        float acc = bd2[t];
        #pragma unroll
        for (int f = 0; f < 72; ++f) acc += r[f] * Wd2[f * 24 + t];
        float part = __shfl_xor(acc, 1);
        p[g * 24 + t] = 1.f / (1.f + __expf(part - acc));
    }
}

__launch_bounds__(256)
__global__ void dense1_kernel(const float* __restrict__ p,
                              const float* __restrict__ Wl1,
                              const float* __restrict__ bl1,
                              float*       __restrict__ y1)
{
    const int idx = blockIdx.x * 256 + threadIdx.x;
    if (idx >= B_GR * 96) return;
    const int row = idx / 96, c = idx - row * 96;
    float acc = bl1[c];
    const float* pr = p + row * 24;
    #pragma unroll
    for (int f = 0; f < 24; ++f) acc += pr[f] * Wl1[f * 96 + c];
    y1[idx] = acc;
}

template<int C>
__launch_bounds__(256)
__global__ void stats_kernel(const float* __restrict__ y, float* __restrict__ st)
{
    const int c = blockIdx.x;
    float s = 0.f, q = 0.f;
    for (int r = threadIdx.x; r < B_GR; r += 256) {
        const float v = y[r * C + c];
        s += v; q += v * v;
    }
    __shared__ float ss[256], qq[256];
    ss[threadIdx.x] = s; qq[threadIdx.x] = q;
    __syncthreads();
    for (int off = 128; off > 0; off >>= 1) {
        if (threadIdx.x < off) {
            ss[threadIdx.x] += ss[threadIdx.x + off];
            qq[threadIdx.x] += qq[threadIdx.x + off];
        }
        __syncthreads();
    }
    if (threadIdx.x == 0) {
        const float mean = ss[0] / (float)B_GR;
        const float var  = qq[0] / (float)B_GR - mean * mean;
        st[c]     = mean;
        st[C + c] = rsqrtf(var + 1e-5f);
    }
}

__launch_bounds__(256)
__global__ void dense2_kernel(const float* __restrict__ y1,
                              const float* __restrict__ st1,
                              const float* __restrict__ g1,
                              const float* __restrict__ be1,
                              const float* __restrict__ Wl2,
                              const float* __restrict__ bl2,
                              float*       __restrict__ y2)
{
    __shared__ float h[4 * 96];
    const int r0 = blockIdx.x * 4;
    for (int e = threadIdx.x; e < 4 * 96; e += 256) {
        const int rr = e / 96, c = e - rr * 96;
        float v = y1[(r0 + rr) * 96 + c];
        v = (v - st1[c]) * st1[96 + c] * g1[c] + be1[c];
        h[e] = fmaxf(v, 0.f);
    }
    __syncthreads();
    for (int e = threadIdx.x; e < 4 * 63; e += 256) {
        const int rr = e / 63, o = e - rr * 63;
        float acc = bl2[o];
        #pragma unroll
        for (int f = 0; f < 96; ++f) acc += h[rr * 96 + f] * Wl2[f * 63 + o];
        y2[(r0 + rr) * 63 + o] = acc;
    }
}

__launch_bounds__(320)
__global__ void dense3_kernel(const float* __restrict__ y2,
                              const float* __restrict__ st2,
                              const float* __restrict__ g2,
                              const float* __restrict__ be2,
                              const float* __restrict__ Wl3,
                              const float* __restrict__ bl3,
                              float*       __restrict__ out)
{
    __shared__ float h[2 * 63];
    const int r0 = blockIdx.x * 2;
    for (int e = threadIdx.x; e < 2 * 63; e += 320) {
        const int rr = e / 63, c = e - rr * 63;
        float v = y2[(r0 + rr) * 63 + c];
        v = (v - st2[c]) * st2[63 + c] * g2[c] + be2[c];
        h[e] = fmaxf(v, 0.f);
    }
    __syncthreads();
    for (int e = threadIdx.x; e < 2 * 138; e += 320) {
        const int rr = e / 138, o = e - rr * 138;
        float acc = bl3[o];
        #pragma unroll
        for (int f = 0; f < 63; ++f) acc += h[rr * 63 + f] * Wl3[f * 138 + o];
        out[(r0 + rr) * 138 + o] = 1.f / (1.f + __expf(-acc));
    }
}

extern "C" void kernel_launch(void* const* d_in, const int* in_sizes, int n_in,
                              void* d_out, int out_size, void* d_ws, size_t ws_size,
                              hipStream_t stream)
{
    (void)in_sizes; (void)n_in; (void)out_size; (void)ws_size;

    const float* af  = (const float*)d_in[0];
    const float* Ws1 = (const float*)d_in[1];
    const float* Wn1 = (const float*)d_in[2];
    const float* b1  = (const float*)d_in[3];
    const float* Ws2 = (const float*)d_in[4];
    const float* Wn2 = (const float*)d_in[5];
    const float* b2  = (const float*)d_in[6];
    const float* Ws3 = (const float*)d_in[7];
    const float* Wn3 = (const float*)d_in[8];
    const float* b3  = (const float*)d_in[9];
    const float* Ws4 = (const float*)d_in[10];
    const float* Wn4 = (const float*)d_in[11];
    const float* b4  = (const float*)d_in[12];
    const float* Wd2 = (const float*)d_in[13];
    const float* bd2 = (const float*)d_in[14];
    const float* Wl1 = (const float*)d_in[15];
    const float* bl1 = (const float*)d_in[16];
    const float* g1  = (const float*)d_in[17];
    const float* be1 = (const float*)d_in[18];
    const float* Wl2 = (const float*)d_in[19];
    const float* bl2 = (const float*)d_in[20];
    const float* g2  = (const float*)d_in[21];
    const float* be2 = (const float*)d_in[22];
    const float* Wl3 = (const float*)d_in[23];
    const float* bl3 = (const float*)d_in[24];
    const int*   nbr = (const int*)d_in[25];
    const int*   deg = (const int*)d_in[26];
    const int*   mem = (const int*)d_in[27];

    float* ws = (float*)d_ws;
    // Regions (floats):
    //   A: PADCAP*27  x1 (sorted), then x3 (sorted), then head scratch
    //   B: PADCAP*36  S (conv1, [PADCAP][16] fp32) then x2 (sorted), then x4o
    //   Zr: PADCAP*32 Z (conv1, [4][PADCAP][16] bf16)
    float* A = ws;
    float* B = A + (size_t)PADCAP * 27;
    float* Zr = B + (size_t)PADCAP * 36;
    int*   idx    = (int*)(Zr + (size_t)PADCAP * 32);   // PADCAP
    int*   rank   = idx + PADCAP;                       // N_ATOMS
    int*   degs_s = rank + N_ATOMS;                     // PADCAP
    int4*  nbrs_s = (int4*)(degs_s + PADCAP);           // PADCAP int4 (sorted ranks)
    int4*  nbro_s = nbrs_s + PADCAP;                    // PADCAP int4 (original ids)
    int*   ctr    = (int*)(nbro_s + PADCAP);            // 16 ints

    float* x1  = A;
    float* Sb  = B;                          // S lives in x2's slot (dead during conv1)
    unsigned short* Zb = (unsigned short*)Zr;
    float* x2  = B;
    float* x3  = A;
    float* x4o = B;                          // original-order conv4 output
    float* p   = A;                          // head scratch reuses A (x3 dead after conv4)
    float* y1  = A + 393216;                 // B_GR*96
    float* y2  = A + 393216 + 1572864;       // B_GR*63
    float* st1 = A + 393216 + 1572864 + 1032192;        // 192
    float* st2 = st1 + 192;                              // 126

    // ---- degree-sort prep (permutation may vary run-to-run; per-atom math identical) ----
    zero_kernel<<<1, 16, 0, stream>>>(ctr);
    fill_kernel<<<PADCAP / 256, 256, 0, stream>>>(idx, degs_s, nbrs_s, nbro_s);
    hist_kernel<<<1024, 256, 0, stream>>>(deg, ctr);
    offsets_kernel<<<1, 1, 0, stream>>>(ctr);
    scatter_kernel<<<(N_ATOMS + 255) / 256, 256, 0, stream>>>(deg, ctr, idx, rank, degs_s);
    nbrprep_kernel<<<(N_ATOMS + 255) / 256, 256, 0, stream>>>(nbr, rank, nbrs_s, nbro_s);

    // ---- conv1: balanced fused project + quad-parallel combine ----
    conv1_project<<<PADCAP / TA, 256, 0, stream>>>(af, Ws1, Wn1, b1, degs_s, idx, Sb, Zb);
    conv1_combine<<<PADCAP / 64, 256, 0, stream>>>(Sb, Zb, nbrs_s, degs_s, x1);

    // ---- conv2-4: R14-proven fused kernels (scalar loads, odd FIP) ----
    conv_fused5<15, 17, 20, false><<<PADCAP / TA, NTHR, 0, stream>>>
        (x1, nbrs_s, Ws2, Wn2, b2, degs_s, idx, x2);
    conv_fused5<20, 21, 27, false><<<PADCAP / TA, NTHR, 0, stream>>>
        (x2, nbrs_s, Ws3, Wn3, b3, degs_s, idx, x3);
    conv_fused5<27, 29, 36, true ><<<PADCAP / TA, NTHR, 0, stream>>>
        (x3, nbrs_s, Ws4, Wn4, b4, degs_s, idx, x4o);

    readout_kernel<<<B_GR, 64, 0, stream>>>(x4o, mem, Wd2, bd2, p);

    dense1_kernel<<<(B_GR * 96) / 256, 256, 0, stream>>>(p, Wl1, bl1, y1);
    stats_kernel<96><<<96, 256, 0, stream>>>(y1, st1);
    dense2_kernel<<<B_GR / 4, 256, 0, stream>>>(y1, st1, g1, be1, Wl2, bl2, y2);
    stats_kernel<63><<<63, 256, 0, stream>>>(y2, st2);
    dense3_kernel<<<B_GR / 2, 320, 0, stream>>>(y2, st2, g2, be2, Wl3, bl3, (float*)d_out);
}

// Round 18
// 652.717 us; speedup vs baseline: 1.3441x; 1.3441x over previous
//
#include <hip/hip_runtime.h>
#include <hip/hip_bf16.h>

#define N_ATOMS 400000
#define MAX_D   4
#define NDEG_   5
#define B_GR    16384
#define NTASK   12
#define AT      256                 // bin alignment
#define TA      64                  // atoms per conv tile (divides AT)
#define NTHR    512                 // 8 waves
#define PADCAP  401408              // 1568 * 256 >= N + 5*(AT-1)

__device__ __forceinline__ float selu_f(float x) {
    const float a = 1.6732632423543772f, s = 1.0507009873554805f;
    return x > 0.f ? s * x : s * a * (__expf(x) - 1.f);
}

// ===================== degree-sort prep =====================
// ctr layout (ints): [0..4] counts, [5..9] cursor, [10..15] bin offsets
__global__ void zero_kernel(int* ctr) {
    if (threadIdx.x < 10) ctr[threadIdx.x] = 0;
}

// Also zero-inits neighbor tables: padding lanes in mixed tiles execute
// unconditional (tile-degree-templated) neighbor loads, so padding slots must
// point at dummy row 0, not garbage.
__launch_bounds__(256)
__global__ void fill_kernel(int* idx, int* degs_s, int4* nbrs_s, int4* nbro_s) {
    const int e = blockIdx.x * 256 + threadIdx.x;
    if (e < PADCAP) {
        idx[e] = -1;
        degs_s[e] = -1;
        nbrs_s[e] = make_int4(0, 0, 0, 0);
        nbro_s[e] = make_int4(0, 0, 0, 0);
    }
}

__launch_bounds__(256)
__global__ void hist_kernel(const int* __restrict__ deg, int* ctr) {
    __shared__ int h[NDEG_];
    if (threadIdx.x < NDEG_) h[threadIdx.x] = 0;
    __syncthreads();
    for (int i = blockIdx.x * 256 + threadIdx.x; i < N_ATOMS; i += gridDim.x * 256)
        atomicAdd(&h[deg[i]], 1);
    __syncthreads();
    if (threadIdx.x < NDEG_ && h[threadIdx.x]) atomicAdd(&ctr[threadIdx.x], h[threadIdx.x]);
}

__global__ void offsets_kernel(int* ctr) {
    if (threadIdx.x == 0) {
        int run = 0;
        for (int d = 0; d < NDEG_; ++d) {
            ctr[10 + d] = run;
            run += ctr[d];
            run = (run + AT - 1) & ~(AT - 1);
        }
        ctr[15] = run;
    }
}

// Hierarchical scatter: per-block LDS histogram -> ONE global atomicAdd per
// (block, degree) -> intra-block rank from LDS counter.
__launch_bounds__(256)
__global__ void scatter_kernel(const int* __restrict__ deg, int* ctr,
                               int* idx, int* rank, int* degs_s) {
    __shared__ int h[NDEG_];
    __shared__ int base[NDEG_];
    const int i = blockIdx.x * 256 + threadIdx.x;
    const int d = (i < N_ATOMS) ? deg[i] : -1;
    if (threadIdx.x < NDEG_) h[threadIdx.x] = 0;
    __syncthreads();
    int intra = 0;
    if (i < N_ATOMS) intra = atomicAdd(&h[d], 1);            // LDS atomic
    __syncthreads();
    if (threadIdx.x < NDEG_ && h[threadIdx.x] > 0)
        base[threadIdx.x] = atomicAdd(&ctr[5 + threadIdx.x], h[threadIdx.x]);
    __syncthreads();
    if (i < N_ATOMS) {
        const int p = ctr[10 + d] + base[d] + intra;
        idx[p] = i;
        rank[i] = p;
        degs_s[p] = d;
    }
}

// Emits BOTH sorted-rank neighbors (layers 2-4) and original-id neighbors (conv1).
__launch_bounds__(256)
__global__ void nbrprep_kernel(const int* __restrict__ nbr, const int* __restrict__ rank,
                               int4* __restrict__ nbrs_s, int4* __restrict__ nbro_s) {
    const int i = blockIdx.x * 256 + threadIdx.x;
    if (i >= N_ATOMS) return;
    const int p = rank[i];
    const int4 nb = *reinterpret_cast<const int4*>(nbr + (size_t)i * MAX_D);
    nbro_s[p] = nb;
    nbrs_s[p] = make_int4(rank[nb.x], rank[nb.y], rank[nb.z], rank[nb.w]);
}

// ===================== conv body, templated on TILE DEGREE =====================
// DEG is compile-time -> phase A's neighbor loads are UNCONDITIONAL straight-line
// code the compiler can software-pipeline (the per-atom `if (d>k)` divergent
// loads of R10-R13 blocked all pipelining: VGPR=8, each load serialized at full
// memory latency). R14-measured: VGPR 20, 1.17 TB/s, conv1 231us.
// (R15's float4 variant regressed conv2-4: bank conflicts 775k->2.5M. R16/R17's
// weight-projection split never beat this kernel. Scalar + odd FIP is the
// verified optimum for this structure.)
template<int FI, int FIP, int FO, bool FIRST, bool SCATTER_OUT, int DEG>
__device__ __forceinline__ void conv_body(const float* __restrict__ x,
                                          const float* __restrict__ Ws,
                                          const float* __restrict__ Wn,
                                          const float* __restrict__ bias,
                                          const int*   __restrict__ idx,
                                          float*       __restrict__ outs,
                                          float (*__restrict__ xt)[FIP],
                                          float (*__restrict__ nt)[FIP],
                                          const int*  s_a,
                                          const int4* s_nb,
                                          int pb, int tid)
{
    // ---- phase A: coalesced gather, unconditional loads, pipelinable ----
    #pragma unroll 2
    for (int e = tid; e < TA * FI; e += NTHR) {
        const int al = e / FI, f = e - al * FI;
        const int4 nb = s_nb[al];
        const float xv = x[(size_t)s_a[al] * FI + f];
        float s = 0.f;
        if (DEG > 0) s += x[(size_t)nb.x * FI + f];
        if (DEG > 1) s += x[(size_t)nb.y * FI + f];
        if (DEG > 2) s += x[(size_t)nb.z * FI + f];
        if (DEG > 3) s += x[(size_t)nb.w * FI + f];
        xt[al][f] = xv;
        nt[al][f] = s;
    }
    __syncthreads();

    // ---- phase B: wave w -> output chunk w; all 64 lanes = atoms; scalar weights ----
    const int w = __builtin_amdgcn_readfirstlane(tid >> 6);   // wave id, SGPR
    const int l = tid & 63;                                   // lane = atom
    constexpr int OPG = (FO + 7) / 8;
    const int o0 = w * OPG;                                   // SGPR
    const float* __restrict__ wsd = Ws + (DEG * FI) * FO + o0;
    const float* __restrict__ wnd = Wn + (DEG * FI) * FO + o0;
    const float* __restrict__ bb  = bias + DEG * FO + o0;

    float acc[OPG];
    #pragma unroll
    for (int oo = 0; oo < OPG; ++oo)
        acc[oo] = (o0 + oo < FO) ? bb[oo] : 0.f;

    for (int f = 0; f < FI; ++f) {
        const float xv = xt[l][f];
        const float nv = nt[l][f];
        const float* __restrict__ wsf = wsd + f * FO;
        const float* __restrict__ wnf = wnd + f * FO;
        #pragma unroll
        for (int oo = 0; oo < OPG; ++oo) {
            if (o0 + oo < FO)
                acc[oo] = fmaf(xv, wsf[oo], fmaf(nv, wnf[oo], acc[oo]));
        }
    }

    int row; bool store;
    if (SCATTER_OUT) { row = idx[pb + l]; store = (row >= 0); }
    else             { row = pb + l;      store = true; }
    if (store) {
        float* __restrict__ orow = outs + (size_t)row * FO + o0;
        #pragma unroll
        for (int oo = 0; oo < OPG; ++oo)
            if (o0 + oo < FO) orow[oo] = selu_f(acc[oo]);
    }
}

// TA=64-atom DEGREE-UNIFORM tiles (bins 256-aligned, 64 | 256 -> one degree
// per tile; padding lanes use dummy row 0 and are discarded). 512 threads.
template<int FI, int FIP, int FO, bool FIRST, bool SCATTER_OUT>
__launch_bounds__(NTHR)
__global__ void conv_fused5(const float* __restrict__ x,     // FIRST: af (orig order), else x_prev (sorted)
                            const int4*  __restrict__ nbr_,  // FIRST: original ids, else sorted ranks
                            const float* __restrict__ Ws,
                            const float* __restrict__ Wn,
                            const float* __restrict__ bias,
                            const int*   __restrict__ degs_s,
                            const int*   __restrict__ idx,
                            float*       __restrict__ outs)
{
    __shared__ float xt[TA][FIP];
    __shared__ float nt[TA][FIP];
    __shared__ int   s_a[TA];
    __shared__ int4  s_nb[TA];

    const int pb = blockIdx.x * TA;
    const int dfirst = degs_s[pb];
    if (dfirst < 0) return;                       // whole tile is padding
    const int tid = threadIdx.x;

    if (tid < TA) {
        const int p = pb + tid;
        int a = FIRST ? idx[p] : p;
        s_a[tid] = (a < 0) ? 0 : a;               // padding: dummy row 0
        s_nb[tid] = nbr_[p];                      // padding: zeroed by fill_kernel
    }
    __syncthreads();

    switch (__builtin_amdgcn_readfirstlane(dfirst)) {
    case 0: conv_body<FI, FIP, FO, FIRST, SCATTER_OUT, 0>(x, Ws, Wn, bias, idx, outs, xt, nt, s_a, s_nb, pb, tid); break;
    case 1: conv_body<FI, FIP, FO, FIRST, SCATTER_OUT, 1>(x, Ws, Wn, bias, idx, outs, xt, nt, s_a, s_nb, pb, tid); break;
    case 2: conv_body<FI, FIP, FO, FIRST, SCATTER_OUT, 2>(x, Ws, Wn, bias, idx, outs, xt, nt, s_a, s_nb, pb, tid); break;
    case 3: conv_body<FI, FIP, FO, FIRST, SCATTER_OUT, 3>(x, Ws, Wn, bias, idx, outs, xt, nt, s_a, s_nb, pb, tid); break;
    default: conv_body<FI, FIP, FO, FIRST, SCATTER_OUT, 4>(x, Ws, Wn, bias, idx, outs, xt, nt, s_a, s_nb, pb, tid); break;
    }
}

// ===================== GraphGather readout + softmax head =====================
// x4o is in ORIGINAL atom order -> sequential row reads per graph segment.
__launch_bounds__(64)
__global__ void readout_kernel(const float* __restrict__ x4o,
                               const int*   __restrict__ mem,
                               const float* __restrict__ Wd2,
                               const float* __restrict__ bd2,
                               float*       __restrict__ p)
{
    const int g = blockIdx.x;
    const int t = threadIdx.x;

    int lo = 0, hi = N_ATOMS;                    // lower_bound(g)
    while (lo < hi) { int mid = (lo + hi) >> 1; if (mem[mid] < g) lo = mid + 1; else hi = mid; }
    int lo2 = lo, hi2 = N_ATOMS;                 // lower_bound(g+1)
    while (lo2 < hi2) { int mid = (lo2 + hi2) >> 1; if (mem[mid] < g + 1) lo2 = mid + 1; else hi2 = mid; }

    __shared__ float r[72];
    if (t < 36) {
        float s = 0.f, m = -3.4e38f;
        for (int a = lo; a < lo2; ++a) {
            float v = x4o[(size_t)a * 36 + t];
            s += v;
            m = fmaxf(m, v);
        }
        if (lo2 == lo) m = 0.f;                  // empty graph -> 0
        r[t]      = selu_f(s);
        r[36 + t] = selu_f(m);
    }
    __syncthreads();
    if (t < 24) {
        float acc = bd2[t];
        #pragma unroll
        for (int f = 0; f < 72; ++f) acc += r[f] * Wd2[f * 24 + t];
        float part = __shfl_xor(acc, 1);
        p[g * 24 + t] = 1.f / (1.f + __expf(part - acc));
    }
}

__launch_bounds__(256)
__global__ void dense1_kernel(const float* __restrict__ p,
                              const float* __restrict__ Wl1,
                              const float* __restrict__ bl1,
                              float*       __restrict__ y1)
{
    const int idx = blockIdx.x * 256 + threadIdx.x;
    if (idx >= B_GR * 96) return;
    const int row = idx / 96, c = idx - row * 96;
    float acc = bl1[c];
    const float* pr = p + row * 24;
    #pragma unroll
    for (int f = 0; f < 24; ++f) acc += pr[f] * Wl1[f * 96 + c];
    y1[idx] = acc;
}

template<int C>
__launch_bounds__(256)
__global__ void stats_kernel(const float* __restrict__ y, float* __restrict__ st)
{
    const int c = blockIdx.x;
    float s = 0.f, q = 0.f;
    for (int r = threadIdx.x; r < B_GR; r += 256) {
        const float v = y[r * C + c];
        s += v; q += v * v;
    }
    __shared__ float ss[256], qq[256];
    ss[threadIdx.x] = s; qq[threadIdx.x] = q;
    __syncthreads();
    for (int off = 128; off > 0; off >>= 1) {
        if (threadIdx.x < off) {
            ss[threadIdx.x] += ss[threadIdx.x + off];
            qq[threadIdx.x] += qq[threadIdx.x + off];
        }
        __syncthreads();
    }
    if (threadIdx.x == 0) {
        const float mean = ss[0] / (float)B_GR;
        const float var  = qq[0] / (float)B_GR - mean * mean;
        st[c]     = mean;
        st[C + c] = rsqrtf(var + 1e-5f);
    }
}

__launch_bounds__(256)
__global__ void dense2_kernel(const float* __restrict__ y1,
                              const float* __restrict__ st1,
                              const float* __restrict__ g1,
                              const float* __restrict__ be1,
                              const float* __restrict__ Wl2,
                              const float* __restrict__ bl2,
                              float*       __restrict__ y2)
{
    __shared__ float h[4 * 96];
    const int r0 = blockIdx.x * 4;
    for (int e = threadIdx.x; e < 4 * 96; e += 256) {
        const int rr = e / 96, c = e - rr * 96;
        float v = y1[(r0 + rr) * 96 + c];
        v = (v - st1[c]) * st1[96 + c] * g1[c] + be1[c];
        h[e] = fmaxf(v, 0.f);
    }
    __syncthreads();
    for (int e = threadIdx.x; e < 4 * 63; e += 256) {
        const int rr = e / 63, o = e - rr * 63;
        float acc = bl2[o];
        #pragma unroll
        for (int f = 0; f < 96; ++f) acc += h[rr * 96 + f] * Wl2[f * 63 + o];
        y2[(r0 + rr) * 63 + o] = acc;
    }
}

__launch_bounds__(320)
__global__ void dense3_kernel(const float* __restrict__ y2,
                              const float* __restrict__ st2,
                              const float* __restrict__ g2,
                              const float* __restrict__ be2,
                              const float* __restrict__ Wl3,
                              const float* __restrict__ bl3,
                              float*       __restrict__ out)
{
    __shared__ float h[2 * 63];
    const int r0 = blockIdx.x * 2;
    for (int e = threadIdx.x; e < 2 * 63; e += 320) {
        const int rr = e / 63, c = e - rr * 63;
        float v = y2[(r0 + rr) * 63 + c];
        v = (v - st2[c]) * st2[63 + c] * g2[c] + be2[c];
        h[e] = fmaxf(v, 0.f);
    }
    __syncthreads();
    for (int e = threadIdx.x; e < 2 * 138; e += 320) {
        const int rr = e / 138, o = e - rr * 138;
        float acc = bl3[o];
        #pragma unroll
        for (int f = 0; f < 63; ++f) acc += h[rr * 63 + f] * Wl3[f * 138 + o];
        out[(r0 + rr) * 138 + o] = 1.f / (1.f + __expf(-acc));
    }
}

extern "C" void kernel_launch(void* const* d_in, const int* in_sizes, int n_in,
                              void* d_out, int out_size, void* d_ws, size_t ws_size,
                              hipStream_t stream)
{
    (void)in_sizes; (void)n_in; (void)out_size; (void)ws_size;

    const float* af  = (const float*)d_in[0];
    const float* Ws1 = (const float*)d_in[1];
    const float* Wn1 = (const float*)d_in[2];
    const float* b1  = (const float*)d_in[3];
    const float* Ws2 = (const float*)d_in[4];
    const float* Wn2 = (const float*)d_in[5];
    const float* b2  = (const float*)d_in[6];
    const float* Ws3 = (const float*)d_in[7];
    const float* Wn3 = (const float*)d_in[8];
    const float* b3  = (const float*)d_in[9];
    const float* Ws4 = (const float*)d_in[10];
    const float* Wn4 = (const float*)d_in[11];
    const float* b4  = (const float*)d_in[12];
    const float* Wd2 = (const float*)d_in[13];
    const float* bd2 = (const float*)d_in[14];
    const float* Wl1 = (const float*)d_in[15];
    const float* bl1 = (const float*)d_in[16];
    const float* g1  = (const float*)d_in[17];
    const float* be1 = (const float*)d_in[18];
    const float* Wl2 = (const float*)d_in[19];
    const float* bl2 = (const float*)d_in[20];
    const float* g2  = (const float*)d_in[21];
    const float* be2 = (const float*)d_in[22];
    const float* Wl3 = (const float*)d_in[23];
    const float* bl3 = (const float*)d_in[24];
    const int*   nbr = (const int*)d_in[25];
    const int*   deg = (const int*)d_in[26];
    const int*   mem = (const int*)d_in[27];

    float* ws = (float*)d_ws;
    // Regions (floats):
    //   A: PADCAP*27  x1 (sorted), then x3 (sorted), then head scratch
    //   B: PADCAP*36  x2 (sorted), then x4o (ORIGINAL atom order)
    float* A = ws;
    float* B = A + (size_t)PADCAP * 27;
    int*   idx    = (int*)(B + (size_t)PADCAP * 36);    // PADCAP
    int*   rank   = idx + PADCAP;                       // N_ATOMS
    int*   degs_s = rank + N_ATOMS;                     // PADCAP
    int4*  nbrs_s = (int4*)(degs_s + PADCAP);           // PADCAP int4 (sorted ranks)
    int4*  nbro_s = nbrs_s + PADCAP;                    // PADCAP int4 (original ids)
    int*   ctr    = (int*)(nbro_s + PADCAP);            // 16 ints

    float* x1  = A;
    float* x2  = B;
    float* x3  = A;
    float* x4o = B;                          // original-order conv4 output
    float* p   = A;                          // head scratch reuses A (x3 dead after conv4)
    float* y1  = A + 393216;                 // B_GR*96
    float* y2  = A + 393216 + 1572864;       // B_GR*63
    float* st1 = A + 393216 + 1572864 + 1032192;        // 192
    float* st2 = st1 + 192;                              // 126

    // ---- degree-sort prep (permutation may vary run-to-run; per-atom math identical) ----
    zero_kernel<<<1, 16, 0, stream>>>(ctr);
    fill_kernel<<<PADCAP / 256, 256, 0, stream>>>(idx, degs_s, nbrs_s, nbro_s);
    hist_kernel<<<1024, 256, 0, stream>>>(deg, ctr);
    offsets_kernel<<<1, 1, 0, stream>>>(ctr);
    scatter_kernel<<<(N_ATOMS + 255) / 256, 256, 0, stream>>>(deg, ctr, idx, rank, degs_s);
    nbrprep_kernel<<<(N_ATOMS + 255) / 256, 256, 0, stream>>>(nbr, rank, nbrs_s, nbro_s);

    // ---- fully-fused conv stack (TA=64, 8 waves, DEG-templated bodies) ----
    conv_fused5<75, 77, 15, true,  false><<<PADCAP / TA, NTHR, 0, stream>>>
        (af, nbro_s, Ws1, Wn1, b1, degs_s, idx, x1);
    conv_fused5<15, 17, 20, false, false><<<PADCAP / TA, NTHR, 0, stream>>>
        (x1, nbrs_s, Ws2, Wn2, b2, degs_s, idx, x2);
    conv_fused5<20, 21, 27, false, false><<<PADCAP / TA, NTHR, 0, stream>>>
        (x2, nbrs_s, Ws3, Wn3, b3, degs_s, idx, x3);
    conv_fused5<27, 29, 36, false, true ><<<PADCAP / TA, NTHR, 0, stream>>>
        (x3, nbrs_s, Ws4, Wn4, b4, degs_s, idx, x4o);

    readout_kernel<<<B_GR, 64, 0, stream>>>(x4o, mem, Wd2, bd2, p);

    dense1_kernel<<<(B_GR * 96) / 256, 256, 0, stream>>>(p, Wl1, bl1, y1);
    stats_kernel<96><<<96, 256, 0, stream>>>(y1, st1);
    dense2_kernel<<<B_GR / 4, 256, 0, stream>>>(y1, st1, g1, be1, Wl2, bl2, y2);
    stats_kernel<63><<<63, 256, 0, stream>>>(y2, st2);
    dense3_kernel<<<B_GR / 2, 320, 0, stream>>>(y2, st2, g2, be2, Wl3, bl3, (float*)d_out);
}